// Round 1
// baseline (106579.651 us; speedup 1.0000x reference)
//
#include <hip/hip_runtime.h>
#include <stdint.h>

#define TSTEPS 512
#define BATCH  64
#define ISZ    512
#define HSZ    1024
#define GSZ    4096
#define NB     256
#define NT     256

static constexpr size_t OFF_XPREV = (size_t)TSTEPS * BATCH * HSZ;      // 33554432
static constexpr size_t OFF_H     = OFF_XPREV + (size_t)BATCH * 1024;  // x_prev padded to max(I,H)=1024
static constexpr size_t OFF_HP    = OFF_H  + (size_t)BATCH * HSZ;
static constexpr size_t OFF_C     = OFF_HP + (size_t)BATCH * HSZ;
static constexpr size_t OFF_M     = OFF_C  + (size_t)BATCH * HSZ;
static constexpr size_t OFF_REG   = OFF_M  + (size_t)BATCH * GSZ;

#define TH_RAW 0.1f
#define TH_QNT 0.1015625f   // quantize(0.1, Q8.8) = rint(25.6)/256 = 26/256

// Q8.8 fake-quantize: clip(rint(x*256), -32768, 32767)/256  (rintf = RTNE = jnp.round)
__device__ __forceinline__ float qA(float x) {
  float v = rintf(x * 256.0f);
  v = fminf(fmaxf(v, -32768.0f), 32767.0f);
  return v * 0.00390625f;
}
// Q2.8 fake-quantize: clip(rint(x*256), -512, 511)/256
__device__ __forceinline__ float qN(float x) {
  float v = rintf(x * 256.0f);
  v = fminf(fmaxf(v, -512.0f), 511.0f);
  return v * 0.00390625f;
}
__device__ __forceinline__ float sigm(float x) { return 1.0f / (1.0f + expf(-x)); }

// ---------------------------------------------------------------------------
// Phase A: quantize x, sequential x-delta scan (exact fixed-point; independent
// of the recurrence). One thread per (b,i). Writes dx[T,B,I] and x_prev output.
// ---------------------------------------------------------------------------
__global__ __launch_bounds__(256) void xscan_kernel(const float* __restrict__ x,
                                                    float* __restrict__ dx,
                                                    float* __restrict__ out_xprev) {
  const int gid = blockIdx.x * blockDim.x + threadIdx.x;  // 0..32767 == b*512+i
  float xp = 0.0f;
  #pragma unroll 8
  for (int t = 0; t < TSTEPS; t++) {
    float xq = qA(x[(size_t)t * (BATCH * ISZ) + gid]);
    float d  = xq - xp;
    float da = fabsf(d);
    dx[(size_t)t * (BATCH * ISZ) + gid] = (da < TH_QNT) ? 0.0f : d;
    if (da >= TH_RAW) xp = xq;
  }
  const int b = gid >> 9;
  const int i = gid & 511;
  out_xprev[(size_t)b * 1024 + i]       = xp;    // first I columns
  out_xprev[(size_t)b * 1024 + 512 + i] = 0.0f;  // zero pad to max(I,H)
}

// ---------------------------------------------------------------------------
// Grid barrier: sense-free epoch barrier, agent-scope (cross-XCD safe).
// ---------------------------------------------------------------------------
__device__ __forceinline__ void gbar(int* cnt, int* gen, int e) {
  __syncthreads();
  if (threadIdx.x == 0) {
    int prev = __hip_atomic_fetch_add(cnt, 1, __ATOMIC_ACQ_REL, __HIP_MEMORY_SCOPE_AGENT);
    if (prev == NB - 1) {
      __hip_atomic_store(cnt, 0, __ATOMIC_RELAXED, __HIP_MEMORY_SCOPE_AGENT);
      __hip_atomic_fetch_add(gen, 1, __ATOMIC_RELEASE, __HIP_MEMORY_SCOPE_AGENT);
    } else {
      while (__hip_atomic_load(gen, __ATOMIC_ACQUIRE, __HIP_MEMORY_SCOPE_AGENT) < e) {
        __builtin_amdgcn_s_sleep(1);
      }
    }
  }
  __syncthreads();
}

// ---------------------------------------------------------------------------
// Phase B: persistent scan. 256 blocks x 256 threads = 65536 = B*H sites.
// Thread (b,j) owns c, h_prev, m[4 gates] in REGISTERS for all 512 steps.
// Per step: 4 dot products (K=512 x-part + K=1024 h-part), gates, h_new,
// then immediately next-step dh into ping-pong buffer. One barrier per step.
// ---------------------------------------------------------------------------
__global__ __launch_bounds__(NT, 1) void scan_kernel(
    const float* __restrict__ dx, const float* __restrict__ w_ih,
    const float* __restrict__ w_hh, const float* __restrict__ b_ih,
    const float* __restrict__ b_hh, float* __restrict__ out,
    float* __restrict__ dh0, float* __restrict__ dh1,
    float* __restrict__ partials, int* cnt, int* gen) {
  const int tid = threadIdx.x;
  const int jj  = tid & 3;
  const int b   = tid >> 2;                 // 0..63
  const int j   = blockIdx.x * 4 + jj;      // 0..1023
  const int g0 = j, g1 = j + HSZ, g2 = j + 2 * HSZ, g3 = j + 3 * HSZ;

  float m0 = b_ih[g0] + b_hh[g0];
  float m1 = b_ih[g1] + b_hh[g1];
  float m2 = b_ih[g2] + b_hh[g2];
  float m3 = b_ih[g3] + b_hh[g3];
  float c = 0.0f, hp = 0.0f, h = 0.0f, regacc = 0.0f;

  // dh for step 0 is identically zero (h0 == h_prev0 == 0)
  dh0[(size_t)b * HSZ + j] = 0.0f;
  int epoch = 1;
  gbar(cnt, gen, epoch); epoch++;

  const float4* __restrict__ wi0 = (const float4*)(w_ih + (size_t)g0 * ISZ);
  const float4* __restrict__ wi1 = (const float4*)(w_ih + (size_t)g1 * ISZ);
  const float4* __restrict__ wi2 = (const float4*)(w_ih + (size_t)g2 * ISZ);
  const float4* __restrict__ wi3 = (const float4*)(w_ih + (size_t)g3 * ISZ);
  const float4* __restrict__ wh0 = (const float4*)(w_hh + (size_t)g0 * HSZ);
  const float4* __restrict__ wh1 = (const float4*)(w_hh + (size_t)g1 * HSZ);
  const float4* __restrict__ wh2 = (const float4*)(w_hh + (size_t)g2 * HSZ);
  const float4* __restrict__ wh3 = (const float4*)(w_hh + (size_t)g3 * HSZ);

  for (int t = 0; t < TSTEPS; t++) {
    float a0 = 0.f, a1 = 0.f, a2 = 0.f, a3 = 0.f;
    {  // x contribution: dx[t,b,:] @ w_ih rows (K=512)
      const float4* __restrict__ xr = (const float4*)(dx + ((size_t)t * BATCH + b) * ISZ);
      #pragma unroll 4
      for (int k = 0; k < ISZ / 4; k++) {
        float4 xv = xr[k]; float4 wv;
        wv = wi0[k]; a0 = fmaf(xv.x, wv.x, fmaf(xv.y, wv.y, fmaf(xv.z, wv.z, fmaf(xv.w, wv.w, a0))));
        wv = wi1[k]; a1 = fmaf(xv.x, wv.x, fmaf(xv.y, wv.y, fmaf(xv.z, wv.z, fmaf(xv.w, wv.w, a1))));
        wv = wi2[k]; a2 = fmaf(xv.x, wv.x, fmaf(xv.y, wv.y, fmaf(xv.z, wv.z, fmaf(xv.w, wv.w, a2))));
        wv = wi3[k]; a3 = fmaf(xv.x, wv.x, fmaf(xv.y, wv.y, fmaf(xv.z, wv.z, fmaf(xv.w, wv.w, a3))));
      }
    }
    {  // h contribution: dh[b,:] @ w_hh rows (K=1024)
      const float* dhb = (t & 1) ? dh1 : dh0;
      const float4* __restrict__ hr = (const float4*)(dhb + (size_t)b * HSZ);
      #pragma unroll 4
      for (int k = 0; k < HSZ / 4; k++) {
        float4 hv = hr[k]; float4 wv;
        wv = wh0[k]; a0 = fmaf(hv.x, wv.x, fmaf(hv.y, wv.y, fmaf(hv.z, wv.z, fmaf(hv.w, wv.w, a0))));
        wv = wh1[k]; a1 = fmaf(hv.x, wv.x, fmaf(hv.y, wv.y, fmaf(hv.z, wv.z, fmaf(hv.w, wv.w, a1))));
        wv = wh2[k]; a2 = fmaf(hv.x, wv.x, fmaf(hv.y, wv.y, fmaf(hv.z, wv.z, fmaf(hv.w, wv.w, a2))));
        wv = wh3[k]; a3 = fmaf(hv.x, wv.x, fmaf(hv.y, wv.y, fmaf(hv.z, wv.z, fmaf(hv.w, wv.w, a3))));
      }
    }
    m0 += a0; m1 += a1; m2 += a2; m3 += a3;

    float pi = qA(m0), pf = qA(m1), pg = qA(m2), po = qA(m3);
    float gi = qN(sigm(pi));
    float gf = qN(sigm(pf));
    float gg = qN(tanhf(pg));
    float go = qN(sigm(po));
    float cn = c * gf + gi * gg;
    c = qA(cn);
    float ct = qN(tanhf(c));
    h = qA(go * ct);
    out[(size_t)t * (BATCH * HSZ) + (size_t)b * HSZ + j] = h;

    if (t < TSTEPS - 1) {  // produce dh for step t+1 (reference computes it at start of t+1)
      float d  = h - hp;
      float da = fabsf(d);
      float dm = (da < TH_QNT) ? 0.0f : d;
      float* nbuf = (t & 1) ? dh0 : dh1;
      nbuf[(size_t)b * HSZ + j] = dm;
      if (da >= TH_RAW) hp = h;
      regacc += fabsf(dm);
    }
    gbar(cnt, gen, epoch); epoch++;
  }

  // final state dump (carry after step T-1)
  out[OFF_H  + (size_t)b * HSZ + j] = h;
  out[OFF_HP + (size_t)b * HSZ + j] = hp;
  out[OFF_C  + (size_t)b * HSZ + j] = c;
  out[OFF_M  + (size_t)b * GSZ + g0] = m0;
  out[OFF_M  + (size_t)b * GSZ + g1] = m1;
  out[OFF_M  + (size_t)b * GSZ + g2] = m2;
  out[OFF_M  + (size_t)b * GSZ + g3] = m3;

  // deterministic reg reduction: block tree-reduce -> partials -> block 0
  __shared__ float red[NT];
  red[tid] = regacc;
  __syncthreads();
  for (int s = NT / 2; s > 0; s >>= 1) {
    if (tid < s) red[tid] += red[tid + s];
    __syncthreads();
  }
  if (tid == 0) partials[blockIdx.x] = red[0];
  gbar(cnt, gen, epoch); epoch++;
  if (blockIdx.x == 0) {
    red[tid] = partials[tid];  // NT == NB == 256
    __syncthreads();
    for (int s = NT / 2; s > 0; s >>= 1) {
      if (tid < s) red[tid] += red[tid + s];
      __syncthreads();
    }
    if (tid == 0) out[OFF_REG] = red[0];
  }
}

// ---------------------------------------------------------------------------
extern "C" void kernel_launch(void* const* d_in, const int* in_sizes, int n_in,
                              void* d_out, int out_size, void* d_ws, size_t ws_size,
                              hipStream_t stream) {
  const float* x    = (const float*)d_in[0];
  const float* w_ih = (const float*)d_in[1];
  const float* w_hh = (const float*)d_in[2];
  const float* b_ih = (const float*)d_in[3];
  const float* b_hh = (const float*)d_in[4];
  float* out = (float*)d_out;

  const size_t dx_elems = (size_t)TSTEPS * BATCH * ISZ;  // 16,777,216 floats = 64 MiB
  float* dx       = (float*)d_ws;
  float* dh0      = dx + dx_elems;
  float* dh1      = dh0 + (size_t)BATCH * HSZ;
  float* partials = dh1 + (size_t)BATCH * HSZ;
  int*   cnt      = (int*)(partials + NB);
  int*   gen      = cnt + 1;
  size_t needed = (size_t)((char*)(gen + 1) - (char*)d_ws);
  if (ws_size < needed) return;  // fail validation cleanly rather than corrupt memory

  hipMemsetAsync(cnt, 0, 2 * sizeof(int), stream);  // barrier state must start at 0 each call
  xscan_kernel<<<128, 256, 0, stream>>>(x, dx, out + OFF_XPREV);
  scan_kernel<<<NB, NT, 0, stream>>>(dx, w_ih, w_hh, b_ih, b_hh, out,
                                     dh0, dh1, partials, cnt, gen);
}